// Round 10
// baseline (1849.913 us; speedup 1.0000x reference)
//
#include <hip/hip_runtime.h>
#include <hip/hip_bf16.h>
#include <math.h>

// ---------------------------------------------------------------------------
// UHG GNN forward (R10):
//   - CSR build rewritten as 3-pass bucket radix (row-bucket -> col-bucket ->
//     exact col). Replaces the 128us/105MB random-write scatter with
//     append-style bucketed passes, AND yields per-col edge lists that are
//     approximately ROW-SORTED (256-row granularity) -> MP gather re-reads
//     cluster in a moving window -> L3 can absorb them.
//   - MP kernel (csr8) unchanged for attribution.
//   - GEMMs register-tiled fp32 (R8-validated), classifier unchanged.
// ---------------------------------------------------------------------------

template<int K, int M, bool WANT_MQ>
__global__ __launch_bounds__(256) void gemm_tile_norm(
    const float* __restrict__ A, const float* __restrict__ W,
    const float* __restrict__ bias, float* __restrict__ H,
    float* __restrict__ mqout, int N)
{
    constexpr int BM  = 128;        // rows per block
    constexpr int KB  = 32;         // k-chunk
    constexpr int NTX = M / 8;      // threads across cols (16 or 8)
    constexpr int NTY = 256 / NTX;  // thread-rows (16 or 32)
    constexpr int TR  = BM / NTY;   // rows per thread (8 or 4)
    constexpr int SA  = BM + 4;     // As stride (pad: conflict-free b128 reads)
    constexpr int SW  = M + 4;

    __shared__ float As[KB][SA];    // transposed: As[k][row]
    __shared__ float Ws[KB][SW];    // Ws[k][col]

    const int tid  = threadIdx.x;
    const int tx   = tid % NTX;
    const int ty   = tid / NTX;
    const int row0 = blockIdx.x * BM;

    float acc[TR][8];
    #pragma unroll
    for (int r = 0; r < TR; ++r)
        #pragma unroll
        for (int c = 0; c < 8; ++c) acc[r][c] = 0.f;

    const int sf4 = tid % 8;   // A staging: float4 slot within k-chunk
    const int sr0 = tid / 8;   // A staging: row within 32-row group

    for (int kc = 0; kc < K / KB; ++kc) {
        if (kc) __syncthreads();
        // stage A chunk, transposed (coalesced global float4 reads)
        #pragma unroll
        for (int t = 0; t < 4; ++t) {
            const int r    = t * 32 + sr0;
            const int grow = row0 + r;
            float4 v = {0.f, 0.f, 0.f, 0.f};
            if (grow < N)
                v = *(const float4*)(A + (size_t)grow * K + kc * KB + sf4 * 4);
            As[sf4 * 4 + 0][r] = v.x;
            As[sf4 * 4 + 1][r] = v.y;
            As[sf4 * 4 + 2][r] = v.z;
            As[sf4 * 4 + 3][r] = v.w;
        }
        // stage W chunk (row-major, contiguous)
        #pragma unroll
        for (int t = 0; t < KB * M / 4 / 256; ++t) {
            const int idx = t * 256 + tid;
            const int kk  = idx / (M / 4);
            const int c4  = idx % (M / 4);
            *(float4*)&Ws[kk][c4 * 4] =
                *(const float4*)(W + (size_t)(kc * KB + kk) * M + c4 * 4);
        }
        __syncthreads();

        #pragma unroll 8
        for (int k = 0; k < KB; ++k) {
            const float4 w0 = *(const float4*)&Ws[k][tx * 8];
            const float4 w1 = *(const float4*)&Ws[k][tx * 8 + 4];
            float a[TR];
            #pragma unroll
            for (int rq = 0; rq < TR / 4; ++rq) {
                const float4 av = *(const float4*)&As[k][ty * TR + rq * 4];
                a[rq * 4 + 0] = av.x; a[rq * 4 + 1] = av.y;
                a[rq * 4 + 2] = av.z; a[rq * 4 + 3] = av.w;
            }
            #pragma unroll
            for (int r = 0; r < TR; ++r) {
                acc[r][0] += a[r] * w0.x;
                acc[r][1] += a[r] * w0.y;
                acc[r][2] += a[r] * w0.z;
                acc[r][3] += a[r] * w0.w;
                acc[r][4] += a[r] * w1.x;
                acc[r][5] += a[r] * w1.y;
                acc[r][6] += a[r] * w1.z;
                acc[r][7] += a[r] * w1.w;
            }
        }
    }

    // fused epilogue: bias + relu + row-normalize (+ mq)
    const float4 b0 = *(const float4*)(bias + tx * 8);
    const float4 b1 = *(const float4*)(bias + tx * 8 + 4);

    #pragma unroll
    for (int r = 0; r < TR; ++r) {
        float v[8];
        v[0] = fmaxf(acc[r][0] + b0.x, 0.f);
        v[1] = fmaxf(acc[r][1] + b0.y, 0.f);
        v[2] = fmaxf(acc[r][2] + b0.z, 0.f);
        v[3] = fmaxf(acc[r][3] + b0.w, 0.f);
        v[4] = fmaxf(acc[r][4] + b1.x, 0.f);
        v[5] = fmaxf(acc[r][5] + b1.y, 0.f);
        v[6] = fmaxf(acc[r][6] + b1.z, 0.f);
        v[7] = fmaxf(acc[r][7] + b1.w, 0.f);

        float ss = 0.f;
        #pragma unroll
        for (int c = 0; c < 8; ++c) ss += v[c] * v[c];
        #pragma unroll
        for (int off = 1; off < NTX; off <<= 1) ss += __shfl_xor(ss, off);

        const float inv = 1.f / (sqrtf(ss) + 1e-9f);
        const int row = row0 + ty * TR + r;
        if (row < N) {
            float4 o0 = {v[0] * inv, v[1] * inv, v[2] * inv, v[3] * inv};
            float4 o1 = {v[4] * inv, v[5] * inv, v[6] * inv, v[7] * inv};
            *(float4*)(H + (size_t)row * M + tx * 8)     = o0;
            *(float4*)(H + (size_t)row * M + tx * 8 + 4) = o1;
            if (WANT_MQ && tx == NTX - 1) {
                const float hl = v[7] * inv;
                mqout[row] = ss * inv * inv - 2.f * hl * hl;  // mink(h,h)
            }
        }
    }
}

// ------------------------- CSR build (bucket radix) -------------------------

// exact per-col histogram (for base/cursor and MP's cnt)
__global__ void hist_kernel(const int* __restrict__ col, int* __restrict__ cnt, int E) {
    const int i = blockIdx.x * blockDim.x + threadIdx.x;
    if (i < E) atomicAdd(&cnt[col[i]], 1);
}

// per-bucket (>>8) histograms for row and col in one pass (LDS-local)
__global__ void hist_buckets(const int* __restrict__ row, const int* __restrict__ col,
                             int* __restrict__ rb, int* __restrict__ cb, int E, int nbk) {
    __shared__ int hr[512];
    __shared__ int hc[512];
    for (int i = threadIdx.x; i < 512; i += blockDim.x) { hr[i] = 0; hc[i] = 0; }
    __syncthreads();
    for (int i = blockIdx.x * blockDim.x + threadIdx.x; i < E; i += gridDim.x * blockDim.x) {
        atomicAdd(&hr[row[i] >> 8], 1);
        atomicAdd(&hc[col[i] >> 8], 1);
    }
    __syncthreads();
    for (int i = threadIdx.x; i < nbk; i += blockDim.x) {
        if (hr[i]) atomicAdd(&rb[i], hr[i]);
        if (hc[i]) atomicAdd(&cb[i], hc[i]);
    }
}

// single-block exclusive scan, n <= 1024 (bucket cursors)
__global__ void scan_small(int* __restrict__ data, int n) {
    __shared__ int s[1024];
    const int t = threadIdx.x;
    const int v = (t < n) ? data[t] : 0;
    s[t] = v;
    __syncthreads();
    for (int off = 1; off < 1024; off <<= 1) {
        const int x = (t >= off) ? s[t - off] : 0;
        __syncthreads();
        s[t] += x;
        __syncthreads();
    }
    if (t < n) data[t] = s[t] - v;   // exclusive
}

#define SCAN_TPB 256
#define SCAN_VPT 4   // 1024 elems per block

__global__ void scan1_kernel(const int* __restrict__ cnt, int* __restrict__ base,
                             int* __restrict__ bsum, int N) {
    __shared__ int s[SCAN_TPB];
    const int t  = threadIdx.x;
    const int i0 = blockIdx.x * (SCAN_TPB * SCAN_VPT) + t * SCAN_VPT;
    int v[SCAN_VPT]; int tot = 0;
    #pragma unroll
    for (int j = 0; j < SCAN_VPT; ++j) {
        v[j] = (i0 + j < N) ? cnt[i0 + j] : 0;
        tot += v[j];
    }
    s[t] = tot;
    __syncthreads();
    for (int off = 1; off < SCAN_TPB; off <<= 1) {
        const int x = (t >= off) ? s[t - off] : 0;
        __syncthreads();
        s[t] += x;
        __syncthreads();
    }
    const int excl = s[t] - tot;
    if (t == SCAN_TPB - 1) bsum[blockIdx.x] = s[SCAN_TPB - 1];
    int run = excl;
    #pragma unroll
    for (int j = 0; j < SCAN_VPT; ++j) {
        if (i0 + j < N) base[i0 + j] = run;
        run += v[j];
    }
}

__global__ void scan2_kernel(int* __restrict__ bsum, int nb) {
    __shared__ int s[SCAN_TPB];
    const int t = threadIdx.x;
    const int v = (t < nb) ? bsum[t] : 0;
    s[t] = v;
    __syncthreads();
    for (int off = 1; off < SCAN_TPB; off <<= 1) {
        const int x = (t >= off) ? s[t - off] : 0;
        __syncthreads();
        s[t] += x;
        __syncthreads();
    }
    if (t < nb) bsum[t] = s[t] - v;   // exclusive
}

__global__ void scan3_kernel(int* __restrict__ base, const int* __restrict__ bsum,
                             int* __restrict__ cursor, int N) {
    const int i = blockIdx.x * blockDim.x + threadIdx.x;
    if (i < N) {
        const int v = base[i] + bsum[i / (SCAN_TPB * SCAN_VPT)];
        base[i]   = v;
        cursor[i] = v;
    }
}

// bucket scatter: append (row,col) pairs to per-bucket regions
template<bool BYROW>
__global__ void bucket_scatter(const int* __restrict__ rin, const int* __restrict__ cin,
                               int* __restrict__ cursor,
                               int* __restrict__ rout, int* __restrict__ cout, int E) {
    const int i = blockIdx.x * blockDim.x + threadIdx.x;
    if (i < E) {
        const int r = rin[i], c = cin[i];
        const int b = (BYROW ? r : c) >> 8;
        const int pos = atomicAdd(&cursor[b], 1);
        rout[pos] = r;
        cout[pos] = c;
    }
}

// exact scatter by col; input is col-bucket-major so writes are L2-local
__global__ void final_scatter(const int* __restrict__ rin, const int* __restrict__ cin,
                              int* __restrict__ cur, int* __restrict__ srow, int E) {
    const int i = blockIdx.x * blockDim.x + threadIdx.x;
    if (i < E) {
        const int c = cin[i];
        const int pos = atomicAdd(&cur[c], 1);
        srow[pos] = rin[i];
    }
}

// ------------------------- CSR message pass (8 edges in flight) ---------------
__global__ __launch_bounds__(256) void message_pass_csr8(
    const float* __restrict__ h, const float* __restrict__ mq,
    const int* __restrict__ srow, const int* __restrict__ base,
    const int* __restrict__ cnt, float* __restrict__ agg, int N)
{
    const int node = (int)((blockIdx.x * 256u + threadIdx.x) >> 6);
    if (node >= N) return;
    const int lane = threadIdx.x & 63;
    const int gl   = lane & 7;       // lane within 8-lane group
    const int g    = lane >> 3;      // group 0..7

    const float4* hb = (const float4*)(h + (size_t)node * 128 + gl * 16);
    const float4 b0 = hb[0];
    const float4 b1 = hb[1];
    const float4 b2 = hb[2];
    const float4 b3 = hb[3];
    const float mqc = mq[node];

    const int nb = cnt[node];
    const int st = base[node];

    float4 acc0 = {0.f,0.f,0.f,0.f}, acc1 = {0.f,0.f,0.f,0.f};
    float4 acc2 = {0.f,0.f,0.f,0.f}, acc3 = {0.f,0.f,0.f,0.f};

    const int iters = (nb + 7) >> 3;
    for (int t = 0; t < iters; ++t) {
        const int ei  = t * 8 + g;
        const bool act = ei < nb;
        const int e   = st + (act ? ei : 0);
        const int r   = srow[e];
        const float4* ha = (const float4*)(h + (size_t)r * 128 + gl * 16);
        const float4 a0 = ha[0];
        const float4 a1 = ha[1];
        const float4 a2 = ha[2];
        const float4 a3 = ha[3];
        const float mqr = mq[r];

        float p = a0.x*b0.x + a0.y*b0.y + a0.z*b0.z + a0.w*b0.w
                + a1.x*b1.x + a1.y*b1.y + a1.z*b1.z + a1.w*b1.w
                + a2.x*b2.x + a2.y*b2.y + a2.z*b2.z + a2.w*b2.w
                + a3.x*b3.x + a3.y*b3.y + a3.z*b3.z;
        p += (gl == 7) ? -a3.w * b3.w : a3.w * b3.w;   // Minkowski sign on elem 127
        p += __shfl_xor(p, 1);
        p += __shfl_xor(p, 2);
        p += __shfl_xor(p, 4);

        const float denom = mqr * mqc + 1e-9f;
        float q = 1.f - (p * p) / denom;
        q = fmaxf(q, 0.f);
        float w = expf(-sqrtf(q));
        w = act ? w : 0.f;

        acc0.x += a0.x*w; acc0.y += a0.y*w; acc0.z += a0.z*w; acc0.w += a0.w*w;
        acc1.x += a1.x*w; acc1.y += a1.y*w; acc1.z += a1.z*w; acc1.w += a1.w*w;
        acc2.x += a2.x*w; acc2.y += a2.y*w; acc2.z += a2.z*w; acc2.w += a2.w*w;
        acc3.x += a3.x*w; acc3.y += a3.y*w; acc3.z += a3.z*w; acc3.w += a3.w*w;
    }

    #pragma unroll
    for (int off = 8; off < 64; off <<= 1) {
        acc0.x += __shfl_xor(acc0.x, off); acc0.y += __shfl_xor(acc0.y, off);
        acc0.z += __shfl_xor(acc0.z, off); acc0.w += __shfl_xor(acc0.w, off);
        acc1.x += __shfl_xor(acc1.x, off); acc1.y += __shfl_xor(acc1.y, off);
        acc1.z += __shfl_xor(acc1.z, off); acc1.w += __shfl_xor(acc1.w, off);
        acc2.x += __shfl_xor(acc2.x, off); acc2.y += __shfl_xor(acc2.y, off);
        acc2.z += __shfl_xor(acc2.z, off); acc2.w += __shfl_xor(acc2.w, off);
        acc3.x += __shfl_xor(acc3.x, off); acc3.y += __shfl_xor(acc3.y, off);
        acc3.z += __shfl_xor(acc3.z, off); acc3.w += __shfl_xor(acc3.w, off);
    }
    if (g == 0) {
        float4* out = (float4*)(agg + (size_t)node * 128 + gl * 16);
        out[0] = acc0;
        out[1] = acc1;
        out[2] = acc2;
        out[3] = acc3;
    }
}

// ------------------------- fallback atomic message pass -------------------------
__global__ __launch_bounds__(256) void message_pass(
    const float* __restrict__ h, const float* __restrict__ mq,
    const int* __restrict__ row, const int* __restrict__ col,
    float* __restrict__ agg, int E)
{
    const int wid  = (int)((blockIdx.x * (unsigned)blockDim.x + threadIdx.x) >> 6);
    const int lane = threadIdx.x & 63;
    if (wid >= E) return;

    const int r = row[wid];
    const int c = col[wid];

    const float a0 = h[(size_t)r * 128 + lane];
    const float a1 = h[(size_t)r * 128 + 64 + lane];
    const float b0 = h[(size_t)c * 128 + lane];
    const float b1 = h[(size_t)c * 128 + 64 + lane];

    float p = a0 * b0 + ((lane == 63) ? -a1 * b1 : a1 * b1);
    #pragma unroll
    for (int off = 1; off < 64; off <<= 1) p += __shfl_xor(p, off);

    const float denom = mq[r] * mq[c] + 1e-9f;
    float q = 1.f - (p * p) / denom;
    q = fmaxf(q, 0.f);
    const float w = expf(-sqrtf(q));

    atomicAdd(&agg[(size_t)c * 128 + lane],      a0 * w);
    atomicAdd(&agg[(size_t)c * 128 + 64 + lane], a1 * w);
}

// ------------------------- classifier -------------------------
__global__ __launch_bounds__(256) void classifier_kernel(
    const float* __restrict__ h3, const float* __restrict__ Wc1,
    const float* __restrict__ bc1, const float* __restrict__ Wc2,
    const float* __restrict__ bc2, float* __restrict__ out, int N)
{
    __shared__ float w1[64 * 32];
    __shared__ float w2[32];
    __shared__ float b1s[32];

    const int tid = threadIdx.x;
    for (int i = tid; i < 64 * 32; i += 256) w1[i] = Wc1[i];
    if (tid < 32) { w2[tid] = Wc2[tid]; b1s[tid] = bc1[tid]; }
    __syncthreads();

    const int n = blockIdx.x * 256 + tid;
    if (n >= N) return;

    float t1[32];
    #pragma unroll
    for (int c = 0; c < 32; ++c) t1[c] = b1s[c];

    const float4* hrow = (const float4*)(h3 + (size_t)n * 64);
    #pragma unroll
    for (int k4 = 0; k4 < 16; ++k4) {
        const float4 hv = hrow[k4];
        const int k = k4 * 4;
        #pragma unroll
        for (int c = 0; c < 32; ++c) {
            t1[c] += hv.x * w1[(k + 0) * 32 + c] + hv.y * w1[(k + 1) * 32 + c]
                   + hv.z * w1[(k + 2) * 32 + c] + hv.w * w1[(k + 3) * 32 + c];
        }
    }

    float z = bc2[0];
    #pragma unroll
    for (int c = 0; c < 32; ++c) z += fmaxf(t1[c], 0.f) * w2[c];
    out[n] = 1.f / (1.f + expf(-z));
}

extern "C" void kernel_launch(void* const* d_in, const int* in_sizes, int n_in,
                              void* d_out, int out_size, void* d_ws, size_t ws_size,
                              hipStream_t stream)
{
    const float* x    = (const float*)d_in[0];
    const int*   ei   = (const int*)  d_in[1];
    const float* W_in = (const float*)d_in[2];
    const float* b_in = (const float*)d_in[3];
    const float* W1   = (const float*)d_in[4];
    const float* b1   = (const float*)d_in[5];
    const float* W2   = (const float*)d_in[6];
    const float* b2   = (const float*)d_in[7];
    const float* Wc1  = (const float*)d_in[8];
    const float* bc1  = (const float*)d_in[9];
    const float* Wc2  = (const float*)d_in[10];
    const float* bc2  = (const float*)d_in[11];
    float* out = (float*)d_out;

    const int N = in_sizes[0] / 256;   // 100000
    const int E = in_sizes[1] / 2;     // 1600000
    const int* row = ei;
    const int* col = ei + E;

    float* bufA = (float*)d_ws;                   // [N,128]  (h buffer; int scratch during build)
    float* bufB = bufA + (size_t)N * 128;         // [N,128]  (agg buffer; int scratch during build)
    float* mq   = bufB + (size_t)N * 128;         // [N]
    int*   cnt  = (int*)(mq + N);                 // [N]
    int*   base = cnt + N;                        // [N]
    int*   cur  = base + N;                       // [N]
    int*   bsum = cur + N;                        // [256]
    int*   srow = bsum + 256;                     // [E]

    // build-time scratch inside bufA/bufB (used strictly before GEMM1)
    int* S    = (int*)bufA;          // [0,512): row-bucket cursor; [512,1024): col-bucket cursor
    int* trr  = S + 1024;            // [E] row-bucketed rows
    int* trc  = trr + E;             // [E] row-bucketed cols
    int* t2r  = (int*)bufB;          // [E] col-bucketed rows
    int* t2c  = t2r + E;             // [E] col-bucketed cols

    const size_t need = ((size_t)N * 257 + (size_t)N * 3 + 256 + (size_t)E) * 4;
    const bool use_csr = ws_size >= need;

    const int scan_blk = (N + SCAN_TPB * SCAN_VPT - 1) / (SCAN_TPB * SCAN_VPT);
    const int NBK = (N + 255) >> 8;              // buckets of 256 nodes (391 for N=100k)
    const int eblk = (E + 255) / 256;

    if (use_csr) {
        hipMemsetAsync(S, 0, 1024 * sizeof(int), stream);
        hipMemsetAsync(cnt, 0, (size_t)N * sizeof(int), stream);
        hist_buckets<<<512, 256, 0, stream>>>(row, col, S, S + 512, E, NBK);
        hist_kernel<<<eblk, 256, 0, stream>>>(col, cnt, E);
        scan_small<<<1, 1024, 0, stream>>>(S, NBK);          // row-bucket cursor
        scan_small<<<1, 1024, 0, stream>>>(S + 512, NBK);    // col-bucket cursor
        scan1_kernel<<<scan_blk, SCAN_TPB, 0, stream>>>(cnt, base, bsum, N);
        scan2_kernel<<<1, SCAN_TPB, 0, stream>>>(bsum, scan_blk);
        scan3_kernel<<<(N + 255) / 256, 256, 0, stream>>>(base, bsum, cur, N);
        bucket_scatter<true><<<eblk, 256, 0, stream>>>(row, col, S, trr, trc, E);
        bucket_scatter<false><<<eblk, 256, 0, stream>>>(trr, trc, S + 512, t2r, t2c, E);
        final_scatter<<<eblk, 256, 0, stream>>>(t2r, t2c, cur, srow, E);
    }

    const int gemm_blk = (N + 127) / 128;
    const int mp_blocks_csr = (N + 3) / 4;
    const int mp_blocks_atm = (E + 3) / 4;

    // Layer 1
    gemm_tile_norm<256, 128, true><<<gemm_blk, 256, 0, stream>>>(x, W_in, b_in, bufA, mq, N);
    if (use_csr) {
        message_pass_csr8<<<mp_blocks_csr, 256, 0, stream>>>(bufA, mq, srow, base, cnt, bufB, N);
    } else {
        hipMemsetAsync(bufB, 0, (size_t)N * 128 * sizeof(float), stream);
        message_pass<<<mp_blocks_atm, 256, 0, stream>>>(bufA, mq, row, col, bufB, E);
    }

    // Layer 2
    gemm_tile_norm<128, 128, true><<<gemm_blk, 256, 0, stream>>>(bufB, W1, b1, bufA, mq, N);
    if (use_csr) {
        message_pass_csr8<<<mp_blocks_csr, 256, 0, stream>>>(bufA, mq, srow, base, cnt, bufB, N);
    } else {
        hipMemsetAsync(bufB, 0, (size_t)N * 128 * sizeof(float), stream);
        message_pass<<<mp_blocks_atm, 256, 0, stream>>>(bufA, mq, row, col, bufB, E);
    }

    // Layer 3: h3 [N,64]
    gemm_tile_norm<128, 64, false><<<gemm_blk, 256, 0, stream>>>(bufB, W2, b2, bufA, nullptr, N);

    // Classifier head
    classifier_kernel<<<(N + 255) / 256, 256, 0, stream>>>(bufA, Wc1, bc1, Wc2, bc2, out, N);
}

// Round 12
// 698.416 us; speedup vs baseline: 2.6487x; 2.6487x over previous
//
#include <hip/hip_runtime.h>
#include <hip/hip_bf16.h>
#include <math.h>

// ---------------------------------------------------------------------------
// UHG GNN forward (R11, resubmitted — R11 bench hit GPU acquisition timeout):
//   - Build path reverted to R9 (hist + 2-level scan + simple scatter): the
//     R10 bucket radix serialized on 391 cursor addresses (559us, VALU 0.1%).
//   - SINGLE experimental change: h stored as bf16 (h only feeds the message
//     pass; agg/GEMM inputs stay fp32). Halves gather bytes 512->256B/edge
//     and halves the h table (51->25.6MB -> better L2 hit). MP converts
//     bf16->fp32 in-register; all arithmetic fp32.
//   - GEMM core / CSR MP structure / classifier unchanged (R8/R9-validated).
// ---------------------------------------------------------------------------

static __device__ __forceinline__ float bf2f(unsigned int s) {
    return __uint_as_float(s << 16);
}
static __device__ __forceinline__ unsigned short f2bf(float f) {
    unsigned u = __float_as_uint(f);
    u += 0x7fffu + ((u >> 16) & 1u);     // round-to-nearest-even
    return (unsigned short)(u >> 16);
}

// Fused GEMM + bias + relu + row-normalize (+ optional mq). Output fp32 or bf16.
template<int K, int M, bool WANT_MQ, bool BF16OUT>
__global__ __launch_bounds__(256) void gemm_tile_norm(
    const float* __restrict__ A, const float* __restrict__ W,
    const float* __restrict__ bias, void* __restrict__ Hout,
    float* __restrict__ mqout, int N)
{
    constexpr int BM  = 128;
    constexpr int KB  = 32;
    constexpr int NTX = M / 8;
    constexpr int NTY = 256 / NTX;
    constexpr int TR  = BM / NTY;
    constexpr int SA  = BM + 4;
    constexpr int SW  = M + 4;

    __shared__ float As[KB][SA];    // transposed: As[k][row]
    __shared__ float Ws[KB][SW];    // Ws[k][col]

    const int tid  = threadIdx.x;
    const int tx   = tid % NTX;
    const int ty   = tid / NTX;
    const int row0 = blockIdx.x * BM;

    float acc[TR][8];
    #pragma unroll
    for (int r = 0; r < TR; ++r)
        #pragma unroll
        for (int c = 0; c < 8; ++c) acc[r][c] = 0.f;

    const int sf4 = tid % 8;
    const int sr0 = tid / 8;

    for (int kc = 0; kc < K / KB; ++kc) {
        if (kc) __syncthreads();
        #pragma unroll
        for (int t = 0; t < 4; ++t) {
            const int r    = t * 32 + sr0;
            const int grow = row0 + r;
            float4 v = {0.f, 0.f, 0.f, 0.f};
            if (grow < N)
                v = *(const float4*)(A + (size_t)grow * K + kc * KB + sf4 * 4);
            As[sf4 * 4 + 0][r] = v.x;
            As[sf4 * 4 + 1][r] = v.y;
            As[sf4 * 4 + 2][r] = v.z;
            As[sf4 * 4 + 3][r] = v.w;
        }
        #pragma unroll
        for (int t = 0; t < KB * M / 4 / 256; ++t) {
            const int idx = t * 256 + tid;
            const int kk  = idx / (M / 4);
            const int c4  = idx % (M / 4);
            *(float4*)&Ws[kk][c4 * 4] =
                *(const float4*)(W + (size_t)(kc * KB + kk) * M + c4 * 4);
        }
        __syncthreads();

        #pragma unroll 8
        for (int k = 0; k < KB; ++k) {
            const float4 w0 = *(const float4*)&Ws[k][tx * 8];
            const float4 w1 = *(const float4*)&Ws[k][tx * 8 + 4];
            float a[TR];
            #pragma unroll
            for (int rq = 0; rq < TR / 4; ++rq) {
                const float4 av = *(const float4*)&As[k][ty * TR + rq * 4];
                a[rq * 4 + 0] = av.x; a[rq * 4 + 1] = av.y;
                a[rq * 4 + 2] = av.z; a[rq * 4 + 3] = av.w;
            }
            #pragma unroll
            for (int r = 0; r < TR; ++r) {
                acc[r][0] += a[r] * w0.x;
                acc[r][1] += a[r] * w0.y;
                acc[r][2] += a[r] * w0.z;
                acc[r][3] += a[r] * w0.w;
                acc[r][4] += a[r] * w1.x;
                acc[r][5] += a[r] * w1.y;
                acc[r][6] += a[r] * w1.z;
                acc[r][7] += a[r] * w1.w;
            }
        }
    }

    const float4 b0 = *(const float4*)(bias + tx * 8);
    const float4 b1 = *(const float4*)(bias + tx * 8 + 4);

    #pragma unroll
    for (int r = 0; r < TR; ++r) {
        float v[8];
        v[0] = fmaxf(acc[r][0] + b0.x, 0.f);
        v[1] = fmaxf(acc[r][1] + b0.y, 0.f);
        v[2] = fmaxf(acc[r][2] + b0.z, 0.f);
        v[3] = fmaxf(acc[r][3] + b0.w, 0.f);
        v[4] = fmaxf(acc[r][4] + b1.x, 0.f);
        v[5] = fmaxf(acc[r][5] + b1.y, 0.f);
        v[6] = fmaxf(acc[r][6] + b1.z, 0.f);
        v[7] = fmaxf(acc[r][7] + b1.w, 0.f);

        float ss = 0.f;
        #pragma unroll
        for (int c = 0; c < 8; ++c) ss += v[c] * v[c];
        #pragma unroll
        for (int off = 1; off < NTX; off <<= 1) ss += __shfl_xor(ss, off);

        const float inv = 1.f / (sqrtf(ss) + 1e-9f);
        const int row = row0 + ty * TR + r;
        if (row < N) {
            if (BF16OUT) {
                unsigned short o[8];
                #pragma unroll
                for (int c = 0; c < 8; ++c) o[c] = f2bf(v[c] * inv);
                uint4 pk;
                pk.x = (unsigned)o[0] | ((unsigned)o[1] << 16);
                pk.y = (unsigned)o[2] | ((unsigned)o[3] << 16);
                pk.z = (unsigned)o[4] | ((unsigned)o[5] << 16);
                pk.w = (unsigned)o[6] | ((unsigned)o[7] << 16);
                *(uint4*)((unsigned short*)Hout + (size_t)row * M + tx * 8) = pk;
            } else {
                float4 o0 = {v[0] * inv, v[1] * inv, v[2] * inv, v[3] * inv};
                float4 o1 = {v[4] * inv, v[5] * inv, v[6] * inv, v[7] * inv};
                *(float4*)((float*)Hout + (size_t)row * M + tx * 8)     = o0;
                *(float4*)((float*)Hout + (size_t)row * M + tx * 8 + 4) = o1;
            }
            if (WANT_MQ && tx == NTX - 1) {
                const float hl = v[7] * inv;
                mqout[row] = ss * inv * inv - 2.f * hl * hl;  // mink(h,h), fp32
            }
        }
    }
}

// ------------------------- CSR build (R9-proven) -------------------------

__global__ void hist_kernel(const int* __restrict__ col, int* __restrict__ cnt, int E) {
    const int i = blockIdx.x * blockDim.x + threadIdx.x;
    if (i < E) atomicAdd(&cnt[col[i]], 1);
}

#define SCAN_TPB 256
#define SCAN_VPT 4   // 1024 elems per block

__global__ void scan1_kernel(const int* __restrict__ cnt, int* __restrict__ base,
                             int* __restrict__ bsum, int N) {
    __shared__ int s[SCAN_TPB];
    const int t  = threadIdx.x;
    const int i0 = blockIdx.x * (SCAN_TPB * SCAN_VPT) + t * SCAN_VPT;
    int v[SCAN_VPT]; int tot = 0;
    #pragma unroll
    for (int j = 0; j < SCAN_VPT; ++j) {
        v[j] = (i0 + j < N) ? cnt[i0 + j] : 0;
        tot += v[j];
    }
    s[t] = tot;
    __syncthreads();
    for (int off = 1; off < SCAN_TPB; off <<= 1) {
        const int x = (t >= off) ? s[t - off] : 0;
        __syncthreads();
        s[t] += x;
        __syncthreads();
    }
    const int excl = s[t] - tot;
    if (t == SCAN_TPB - 1) bsum[blockIdx.x] = s[SCAN_TPB - 1];
    int run = excl;
    #pragma unroll
    for (int j = 0; j < SCAN_VPT; ++j) {
        if (i0 + j < N) base[i0 + j] = run;
        run += v[j];
    }
}

__global__ void scan2_kernel(int* __restrict__ bsum, int nb) {
    __shared__ int s[SCAN_TPB];
    const int t = threadIdx.x;
    const int v = (t < nb) ? bsum[t] : 0;
    s[t] = v;
    __syncthreads();
    for (int off = 1; off < SCAN_TPB; off <<= 1) {
        const int x = (t >= off) ? s[t - off] : 0;
        __syncthreads();
        s[t] += x;
        __syncthreads();
    }
    if (t < nb) bsum[t] = s[t] - v;   // exclusive
}

__global__ void scan3_kernel(int* __restrict__ base, const int* __restrict__ bsum,
                             int* __restrict__ cursor, int N) {
    const int i = blockIdx.x * blockDim.x + threadIdx.x;
    if (i < N) {
        const int v = base[i] + bsum[i / (SCAN_TPB * SCAN_VPT)];
        base[i]   = v;
        cursor[i] = v;
    }
}

__global__ void scatter_kernel(const int* __restrict__ row, const int* __restrict__ col,
                               int* __restrict__ cursor, int* __restrict__ srow, int E) {
    const int i = blockIdx.x * blockDim.x + threadIdx.x;
    if (i < E) {
        const int pos = atomicAdd(&cursor[col[i]], 1);
        srow[pos] = row[i];
    }
}

// ------------------------- CSR message pass, bf16 payload ---------------------
// One wave per destination node. Eight 8-lane groups, one edge each per iter.
// Gather 256B/edge (bf16), all math fp32, agg written fp32. No atomics.
__global__ __launch_bounds__(256) void message_pass_csr8bf(
    const unsigned short* __restrict__ h, const float* __restrict__ mq,
    const int* __restrict__ srow, const int* __restrict__ base,
    const int* __restrict__ cnt, float* __restrict__ agg, int N)
{
    const int node = (int)((blockIdx.x * 256u + threadIdx.x) >> 6);
    if (node >= N) return;
    const int lane = threadIdx.x & 63;
    const int gl   = lane & 7;       // lane within 8-lane group (covers 16 elems)
    const int g    = lane >> 3;      // group 0..7

    float b[16];
    {
        const uint4* pb = (const uint4*)(h + (size_t)node * 128 + gl * 16);
        const uint4 u0 = pb[0], u1 = pb[1];
        const unsigned uu[8] = {u0.x, u0.y, u0.z, u0.w, u1.x, u1.y, u1.z, u1.w};
        #pragma unroll
        for (int j = 0; j < 8; ++j) {
            b[2*j]   = bf2f(uu[j] & 0xffffu);
            b[2*j+1] = bf2f(uu[j] >> 16);
        }
    }
    const float mqc = mq[node];
    const int nb = cnt[node];
    const int st = base[node];

    float acc[16];
    #pragma unroll
    for (int j = 0; j < 16; ++j) acc[j] = 0.f;

    const int iters = (nb + 7) >> 3;
    for (int t = 0; t < iters; ++t) {
        const int ei  = t * 8 + g;
        const bool act = ei < nb;
        const int e   = st + (act ? ei : 0);
        const int r   = srow[e];
        float a[16];
        {
            const uint4* pa = (const uint4*)(h + (size_t)r * 128 + gl * 16);
            const uint4 u0 = pa[0], u1 = pa[1];
            const unsigned uu[8] = {u0.x, u0.y, u0.z, u0.w, u1.x, u1.y, u1.z, u1.w};
            #pragma unroll
            for (int j = 0; j < 8; ++j) {
                a[2*j]   = bf2f(uu[j] & 0xffffu);
                a[2*j+1] = bf2f(uu[j] >> 16);
            }
        }
        const float mqr = mq[r];

        float p = 0.f;
        #pragma unroll
        for (int j = 0; j < 16; ++j) p += a[j] * b[j];
        if (gl == 7) p -= 2.f * a[15] * b[15];   // Minkowski sign on elem 127
        p += __shfl_xor(p, 1);
        p += __shfl_xor(p, 2);
        p += __shfl_xor(p, 4);

        const float denom = mqr * mqc + 1e-9f;
        float q = 1.f - (p * p) / denom;
        q = fmaxf(q, 0.f);
        float w = expf(-sqrtf(q));
        w = act ? w : 0.f;

        #pragma unroll
        for (int j = 0; j < 16; ++j) acc[j] += a[j] * w;
    }

    #pragma unroll
    for (int off = 8; off < 64; off <<= 1) {
        #pragma unroll
        for (int j = 0; j < 16; ++j) acc[j] += __shfl_xor(acc[j], off);
    }
    if (g == 0) {
        float4* o = (float4*)(agg + (size_t)node * 128 + gl * 16);
        #pragma unroll
        for (int j = 0; j < 4; ++j) {
            float4 f;
            f.x = acc[4*j + 0]; f.y = acc[4*j + 1];
            f.z = acc[4*j + 2]; f.w = acc[4*j + 3];
            o[j] = f;
        }
    }
}

// ------------------------- fallback atomic message pass (bf16 h) --------------
__global__ __launch_bounds__(256) void message_pass_bf(
    const unsigned short* __restrict__ h, const float* __restrict__ mq,
    const int* __restrict__ row, const int* __restrict__ col,
    float* __restrict__ agg, int E)
{
    const int wid  = (int)((blockIdx.x * (unsigned)blockDim.x + threadIdx.x) >> 6);
    const int lane = threadIdx.x & 63;
    if (wid >= E) return;

    const int r = row[wid];
    const int c = col[wid];

    const float a0 = bf2f(h[(size_t)r * 128 + lane]);
    const float a1 = bf2f(h[(size_t)r * 128 + 64 + lane]);
    const float b0 = bf2f(h[(size_t)c * 128 + lane]);
    const float b1 = bf2f(h[(size_t)c * 128 + 64 + lane]);

    float p = a0 * b0 + ((lane == 63) ? -a1 * b1 : a1 * b1);
    #pragma unroll
    for (int off = 1; off < 64; off <<= 1) p += __shfl_xor(p, off);

    const float denom = mq[r] * mq[c] + 1e-9f;
    float q = 1.f - (p * p) / denom;
    q = fmaxf(q, 0.f);
    const float w = expf(-sqrtf(q));

    atomicAdd(&agg[(size_t)c * 128 + lane],      a0 * w);
    atomicAdd(&agg[(size_t)c * 128 + 64 + lane], a1 * w);
}

// ------------------------- classifier -------------------------
__global__ __launch_bounds__(256) void classifier_kernel(
    const float* __restrict__ h3, const float* __restrict__ Wc1,
    const float* __restrict__ bc1, const float* __restrict__ Wc2,
    const float* __restrict__ bc2, float* __restrict__ out, int N)
{
    __shared__ float w1[64 * 32];
    __shared__ float w2[32];
    __shared__ float b1s[32];

    const int tid = threadIdx.x;
    for (int i = tid; i < 64 * 32; i += 256) w1[i] = Wc1[i];
    if (tid < 32) { w2[tid] = Wc2[tid]; b1s[tid] = bc1[tid]; }
    __syncthreads();

    const int n = blockIdx.x * 256 + tid;
    if (n >= N) return;

    float t1[32];
    #pragma unroll
    for (int c = 0; c < 32; ++c) t1[c] = b1s[c];

    const float4* hrow = (const float4*)(h3 + (size_t)n * 64);
    #pragma unroll
    for (int k4 = 0; k4 < 16; ++k4) {
        const float4 hv = hrow[k4];
        const int k = k4 * 4;
        #pragma unroll
        for (int c = 0; c < 32; ++c) {
            t1[c] += hv.x * w1[(k + 0) * 32 + c] + hv.y * w1[(k + 1) * 32 + c]
                   + hv.z * w1[(k + 2) * 32 + c] + hv.w * w1[(k + 3) * 32 + c];
        }
    }

    float z = bc2[0];
    #pragma unroll
    for (int c = 0; c < 32; ++c) z += fmaxf(t1[c], 0.f) * w2[c];
    out[n] = 1.f / (1.f + expf(-z));
}

extern "C" void kernel_launch(void* const* d_in, const int* in_sizes, int n_in,
                              void* d_out, int out_size, void* d_ws, size_t ws_size,
                              hipStream_t stream)
{
    const float* x    = (const float*)d_in[0];
    const int*   ei   = (const int*)  d_in[1];
    const float* W_in = (const float*)d_in[2];
    const float* b_in = (const float*)d_in[3];
    const float* W1   = (const float*)d_in[4];
    const float* b1   = (const float*)d_in[5];
    const float* W2   = (const float*)d_in[6];
    const float* b2   = (const float*)d_in[7];
    const float* Wc1  = (const float*)d_in[8];
    const float* bc1  = (const float*)d_in[9];
    const float* Wc2  = (const float*)d_in[10];
    const float* bc2  = (const float*)d_in[11];
    float* out = (float*)d_out;

    const int N = in_sizes[0] / 256;   // 100000
    const int E = in_sizes[1] / 2;     // 1600000
    const int* row = ei;
    const int* col = ei + E;

    // workspace layout (~110.4 MB)
    unsigned short* hbf = (unsigned short*)d_ws;          // [N,128] bf16 h
    float* aggF = (float*)(hbf + (size_t)N * 128);        // [N,128] fp32 agg
    float* h3   = aggF + (size_t)N * 128;                 // [N,64]  fp32
    float* mq   = h3 + (size_t)N * 64;                    // [N]
    int*   cnt  = (int*)(mq + N);                         // [N]
    int*   base = cnt + N;                                // [N]
    int*   cur  = base + N;                               // [N]
    int*   bsum = cur + N;                                // [256]
    int*   srow = bsum + 256;                             // [E]

    const size_t need = (size_t)N * 1040 + 1024 + (size_t)E * 4;
    const bool use_csr = ws_size >= need;

    const int scan_blk = (N + SCAN_TPB * SCAN_VPT - 1) / (SCAN_TPB * SCAN_VPT);

    if (use_csr) {
        hipMemsetAsync(cnt, 0, (size_t)N * sizeof(int), stream);
        hist_kernel<<<(E + 255) / 256, 256, 0, stream>>>(col, cnt, E);
        scan1_kernel<<<scan_blk, SCAN_TPB, 0, stream>>>(cnt, base, bsum, N);
        scan2_kernel<<<1, SCAN_TPB, 0, stream>>>(bsum, scan_blk);
        scan3_kernel<<<(N + 255) / 256, 256, 0, stream>>>(base, bsum, cur, N);
        scatter_kernel<<<(E + 255) / 256, 256, 0, stream>>>(row, col, cur, srow, E);
    }

    const int gemm_blk = (N + 127) / 128;
    const int mp_blocks_csr = (N + 3) / 4;
    const int mp_blocks_atm = (E + 3) / 4;

    // Layer 1: h1(bf16) = norm(relu(x @ W_in + b_in)), mq fp32
    gemm_tile_norm<256, 128, true, true><<<gemm_blk, 256, 0, stream>>>(x, W_in, b_in, hbf, mq, N);
    if (use_csr) {
        message_pass_csr8bf<<<mp_blocks_csr, 256, 0, stream>>>(hbf, mq, srow, base, cnt, aggF, N);
    } else {
        hipMemsetAsync(aggF, 0, (size_t)N * 128 * sizeof(float), stream);
        message_pass_bf<<<mp_blocks_atm, 256, 0, stream>>>(hbf, mq, row, col, aggF, E);
    }

    // Layer 2: h2(bf16) = norm(relu(agg1 @ W1 + b1)), mq fp32
    gemm_tile_norm<128, 128, true, true><<<gemm_blk, 256, 0, stream>>>(aggF, W1, b1, hbf, mq, N);
    if (use_csr) {
        message_pass_csr8bf<<<mp_blocks_csr, 256, 0, stream>>>(hbf, mq, srow, base, cnt, aggF, N);
    } else {
        hipMemsetAsync(aggF, 0, (size_t)N * 128 * sizeof(float), stream);
        message_pass_bf<<<mp_blocks_atm, 256, 0, stream>>>(hbf, mq, row, col, aggF, E);
    }

    // Layer 3: h3(fp32) [N,64] = norm(relu(agg2 @ W2 + b2))
    gemm_tile_norm<128, 64, false, false><<<gemm_blk, 256, 0, stream>>>(aggF, W2, b2, h3, nullptr, N);

    // Classifier head
    classifier_kernel<<<(N + 255) / 256, 256, 0, stream>>>(h3, Wc1, bc1, Wc2, bc2, out, N);
}